// Round 4
// baseline (705.886 us; speedup 1.0000x reference)
//
#include <hip/hip_runtime.h>
#include <math.h>

#define N_NODES 4096
#define WORDS   64
#define HID     256
#define VOCAB   50257
#define NCLASS  4
#define N_LEAF  2048
#define RNN_BLOCKS 256     // 1 block/CU -> all resident, spin-wait safe
#define POISON 0x7FFF7FFFu // half2 (NaN,NaN); finite packed rows never match

typedef _Float16 half2_t __attribute__((ext_vector_type(2)));

__device__ __forceinline__ float dot2f(half2_t a, half2_t b, float c) {
#if __has_builtin(__builtin_amdgcn_fdot2)
  return __builtin_amdgcn_fdot2(a, b, c, false);   // v_dot2_f32_f16
#else
  return c + (float)a.x * (float)b.x + (float)a.y * (float)b.y;
#endif
}

__device__ __forceinline__ half2_t f2h2(float f) {
  union { float f; half2_t h; } u; u.f = f; return u.h;
}

__device__ __forceinline__ float fast_rcp(float x) { return __builtin_amdgcn_rcpf(x); }
__device__ __forceinline__ float fast_sigmoid(float x) {        // rcp-based, no IEEE div seq
  return fast_rcp(1.f + __expf(-x));
}
__device__ __forceinline__ float fast_tanh(float x) {           // 1 - 2/(e^{2x}+1); saturates to +-1
  return 1.f - 2.f * fast_rcp(1.f + __expf(2.f * x));
}
__device__ __forceinline__ half2_t pkrtz(float a, float b) {    // single v_cvt_pkrtz_f16_f32
#if __has_builtin(__builtin_amdgcn_cvt_pkrtz)
  return __builtin_bit_cast(half2_t, __builtin_amdgcn_cvt_pkrtz(a, b));
#else
  half2_t v; v.x = (_Float16)a; v.y = (_Float16)b; return v;
#endif
}

// ---------------------------------------------------------------- poison Hpk (the handoff medium)
__global__ void poison_hpk_kernel(unsigned* __restrict__ HpkU) {
  int i = blockIdx.x * blockDim.x + threadIdx.x;
  if (i < N_NODES * (HID / 2)) HpkU[i] = POISON;
}

// ---------------------------------------------------------------- E (HID,VOCAB) f32 -> ETh (VOCAB,HID) f16
__global__ void transpose_f16_kernel(const float* __restrict__ src, _Float16* __restrict__ dst,
                                     int R, int C) {
  __shared__ float tile[32][33];
  int c0 = blockIdx.x * 32, r0 = blockIdx.y * 32;
  int tx = threadIdx.x, ty = threadIdx.y;
#pragma unroll
  for (int j = 0; j < 32; j += 8) {
    int c = c0 + tx, r = r0 + ty + j;
    if (c < C) tile[ty + j][tx] = src[(size_t)r * C + c];
  }
  __syncthreads();
#pragma unroll
  for (int j = 0; j < 32; j += 8) {
    int c = c0 + ty + j, r = r0 + tx;
    if (c < C) dst[(size_t)c * R + r] = (_Float16)tile[tx][ty + j];
  }
}

// ---------------------------------------------------------------- pack U -> half2, layout Upk[(m*4+s)*8192 + j*256 + h]
__global__ void __launch_bounds__(256) pack_u_kernel(
    const float* __restrict__ Uz, const float* __restrict__ Ur, const float* __restrict__ Uh,
    half2_t* __restrict__ Upk) {
  __shared__ float tile[64][259];
  int m = blockIdx.x >> 2, g = blockIdx.x & 3;
  const float* U = m == 0 ? Uz : (m == 1 ? Ur : Uh);
  int t = threadIdx.x;
  for (int r = 0; r < 64; ++r) tile[r][t] = U[(size_t)(g * 64 + r) * 256 + t];
  __syncthreads();
#pragma unroll
  for (int it = 0; it < 32; ++it) {
    int e = it * 256 + t;
    int hl = e & 63, kj = e >> 6, s = kj >> 5, j = kj & 31;
    half2_t v;
    v.x = (_Float16)tile[hl][s * 64 + 2 * j];
    v.y = (_Float16)tile[hl][s * 64 + 2 * j + 1];
    Upk[(size_t)(m * 4 + s) * 8192 + j * 256 + (g * 64 + hl)] = v;
  }
}

// ---------------------------------------------------------------- X[i,h] = sum_w ETh[tree[i,w], h]
__global__ void gather_x_kernel(const int* __restrict__ tree, const half2_t* __restrict__ ETh2,
                                float* __restrict__ X, float* __restrict__ H,
                                half2_t* __restrict__ Hpk) {
  int i = blockIdx.x;
  int t = threadIdx.x;            // 128 threads; thread t covers h = 2t, 2t+1
  __shared__ int vs[WORDS];
  if (t < WORDS) vs[t] = tree[i * WORDS + t];
  __syncthreads();
  float ax = 0.f, ay = 0.f;
#pragma unroll 8
  for (int w = 0; w < WORDS; ++w) {
    half2_t e = ETh2[(size_t)vs[w] * (HID / 2) + t];
    ax += (float)e.x;
    ay += (float)e.y;
  }
  float2 v2; v2.x = ax; v2.y = ay;
  ((float2*)(X + (size_t)i * HID))[t] = v2;
  if (i == 0) {
    ((float2*)H)[t] = v2;                 // node 0 fp32 (for leafmax)
    half2_t hv; hv.x = (_Float16)ax; hv.y = (_Float16)ay;
    Hpk[t] = hv;                          // node 0 packed row (un-poisons it)
  }
}

// ---------------------------------------------------------------- A = X @ W^T for 3 weights
__global__ void __launch_bounds__(256) gemm3_kernel(
    const float* __restrict__ X,
    const float* __restrict__ W0, const float* __restrict__ W1, const float* __restrict__ W2,
    float* __restrict__ A0, float* __restrict__ A1, float* __restrict__ A2) {
  const float* W = blockIdx.z == 0 ? W0 : (blockIdx.z == 1 ? W1 : W2);
  float*       A = blockIdx.z == 0 ? A0 : (blockIdx.z == 1 ? A1 : A2);
  __shared__ float Xs[16][65];
  __shared__ float Ws[16][65];
  int tid = threadIdx.x;
  int m0 = blockIdx.x * 64, n0 = blockIdx.y * 64;
  int tm = (tid / 16) * 4, tn = (tid % 16) * 4;
  int lm = tid >> 2, lk = (tid & 3) * 4;
  float acc[4][4];
#pragma unroll
  for (int a = 0; a < 4; ++a)
#pragma unroll
    for (int b = 0; b < 4; ++b) acc[a][b] = 0.f;

  for (int k0 = 0; k0 < HID; k0 += 16) {
    float4 xv = *(const float4*)(X + (size_t)(m0 + lm) * HID + k0 + lk);
    Xs[lk + 0][lm] = xv.x; Xs[lk + 1][lm] = xv.y; Xs[lk + 2][lm] = xv.z; Xs[lk + 3][lm] = xv.w;
    float4 wv = *(const float4*)(W + (size_t)(n0 + lm) * HID + k0 + lk);
    Ws[lk + 0][lm] = wv.x; Ws[lk + 1][lm] = wv.y; Ws[lk + 2][lm] = wv.z; Ws[lk + 3][lm] = wv.w;
    __syncthreads();
#pragma unroll
    for (int k = 0; k < 16; ++k) {
      float xm[4], wn[4];
#pragma unroll
      for (int u = 0; u < 4; ++u) { xm[u] = Xs[k][tm + u]; wn[u] = Ws[k][tn + u]; }
#pragma unroll
      for (int a = 0; a < 4; ++a)
#pragma unroll
        for (int b = 0; b < 4; ++b) acc[a][b] = fmaf(xm[a], wn[b], acc[a][b]);
    }
    __syncthreads();
  }
#pragma unroll
  for (int a = 0; a < 4; ++a)
#pragma unroll
    for (int b = 0; b < 4; ++b)
      A[(size_t)(m0 + tm + a) * HID + n0 + tn + b] = acc[a][b];
}

// ---------------------------------------------------------------- persistent wavefront GRU scan
// R14 = R13 resubmit (R3 bench was an infra failure; kernel re-audited: barriers matched,
// poll liveness grounded at node 0, LDS write->read pairs all barrier-separated, U-layout
// algebra re-derived). Only change: spin escape 1<<26 -> 1<<22 so any protocol bug
// terminates with poisoned (diagnosable) output instead of a container-killing hang.
//
// Structure: R0's block-cyclic wavefront + asymmetric U split to cut per-step latency:
//   A = ks0 (waves 0-3): big[128]=Uh FULL-K, small[64]=Uz k<128
//   B = ks1 (waves 4-7): big[128]=Ur FULL-K, small[64]=Uz k>=128
// Same per-thread footprint as R0 (128+64 half2) -> same VGPR profile.
// Per node, TWO barriers (was 3):
//   B0: php (parent row) ready.
//   phase1: A: z_lo dot; B: r full dot -> rhp packed, z_hi dot -> zh[] LDS.
//   B1.
//   A: full-K Uh dot IN-REGISTER + whole epilogue (g,c,hn,stores) -- no part[] LDS trip,
//      no B2. B: immediately polls the NEXT node's parent and refills php, OVERLAPPED with
//      A's phase2+epilogue.
// Race audit (all pairs barrier-separated): php written by B post-B1(t), read in phase1(t+1)
// after B0(t+1); zh/rhp written pre-B1(t+1) after B0(t+1), which waits for A's phase2(t)
// reads. A's phase2 touches only rhp/zh/registers, never php.
// All U loops FULLY unrolled (R6 lesson: partial unroll -> alloca -> LDS/scratch catastrophe).
__global__ void
__attribute__((amdgpu_flat_work_group_size(512, 512), amdgpu_waves_per_eu(2, 2)))
rnn_kernel(
    const float* __restrict__ Az, const float* __restrict__ Ar, const float* __restrict__ Ah,
    const half2_t* __restrict__ Upk,
    const float* __restrict__ bz, const float* __restrict__ br, const float* __restrict__ bh,
    const int* __restrict__ edge, float* __restrict__ H, unsigned* HpkU) {
  const int tid = threadIdx.x;
  const int h   = tid & (HID - 1);
  const int ks  = tid >> 8;            // 0 = A (epilogue side), 1 = B (r-gate + poll side)
  __shared__ half2_t php[HID / 2];
  __shared__ half2_t rhp[HID / 2];
  __shared__ float   zh[HID];

  // one-time U load (full unroll -> SSA -> register file)
  // big: A -> Uh (m=2, s=0..3, full K); B -> Ur (m=1, s=0..3, full K)
  // small: A -> Uz s=0,1 (k in [0,128)); B -> Uz s=2,3 (k in [128,256))
  half2_t big[128];
  half2_t small[64];
  {
    const half2_t* mb = Upk + (size_t)(ks ? 4 : 8) * 8192 + h;
#pragma unroll
    for (int j = 0; j < 128; ++j)
      big[j] = mb[(j >> 5) * 8192 + (j & 31) * 256];
    const half2_t* sb = Upk + (size_t)(ks ? 2 : 0) * 8192 + h;
#pragma unroll
    for (int j = 0; j < 64; ++j)
      small[j] = sb[(j >> 5) * 8192 + (j & 31) * 256];
  }
  const float bzv = ks ? 0.f : bz[h];
  const float bhv = ks ? 0.f : bh[h];
  const float brv = ks ? br[h] : 0.f;

  const int i0 = (blockIdx.x == 0) ? RNN_BLOCKS : blockIdx.x;  // node 0 pre-seeded by gather
  const int tl = tid - HID;            // B-side lane id (0..255); pollers are tl<128

  // prologue: A-rows for i0; B polls parent(i0) into php
  float az = 0.f, ah = 0.f, ar = 0.f;
  if (!ks) {
    az = Az[(size_t)i0 * HID + h];
    ah = Ah[(size_t)i0 * HID + h];
  } else {
    ar = Ar[(size_t)i0 * HID + h];
    const int p = edge[2 * i0];        // parent, p < i0
    if (tl < HID / 2) {
      unsigned v = __hip_atomic_load(&HpkU[(size_t)p * (HID / 2) + tl],
                                     __ATOMIC_RELAXED, __HIP_MEMORY_SCOPE_AGENT);
      long spin = 0;
      while (v == POISON) {
        if (++spin > (1L << 22)) break;   // escape hatch (should never trigger)
        v = __hip_atomic_load(&HpkU[(size_t)p * (HID / 2) + tl],
                              __ATOMIC_RELAXED, __HIP_MEMORY_SCOPE_AGENT);
      }
      php[tl] = __builtin_bit_cast(half2_t, v);
    }
  }

  for (int i = i0; i < N_NODES; i += RNN_BLOCKS) {
    __syncthreads();   // B0: parent row resident in php
    half2_t ph2 = php[h >> 1];
    const float phv = (float)((h & 1) ? ph2.y : ph2.x);
    const float4* phq = (const float4*)php;

    // phase 1
    float z0 = 0.f, z1 = 0.f, z2 = 0.f, z3 = 0.f;   // A: z_lo ; B: z_hi
    float r0 = 0.f, r1 = 0.f, r2 = 0.f, r3 = 0.f;   // B: r full-K
    if (ks) {
#pragma unroll
      for (int q = 0; q < 32; ++q) {
        float4 blk = phq[q];
        r0 = dot2f(big[4 * q + 0], f2h2(blk.x), r0);
        r1 = dot2f(big[4 * q + 1], f2h2(blk.y), r1);
        r2 = dot2f(big[4 * q + 2], f2h2(blk.z), r2);
        r3 = dot2f(big[4 * q + 3], f2h2(blk.w), r3);
      }
    }
    {
      const int qo = ks ? 16 : 0;   // A: k in [0,128) ; B: k in [128,256)
#pragma unroll
      for (int q = 0; q < 16; ++q) {
        float4 blk = phq[qo + q];
        z0 = dot2f(small[4 * q + 0], f2h2(blk.x), z0);
        z1 = dot2f(small[4 * q + 1], f2h2(blk.y), z1);
        z2 = dot2f(small[4 * q + 2], f2h2(blk.z), z2);
        z3 = dot2f(small[4 * q + 3], f2h2(blk.w), z3);
      }
    }
    if (ks) {
      const float rg = fast_sigmoid(ar + brv + (r0 + r1) + (r2 + r3));
      float rh = rg * phv;
      float nb = __shfl_xor(rh, 1, 64);
      if ((h & 1) == 0) rhp[h >> 1] = pkrtz(rh, nb);
      zh[h] = (z0 + z1) + (z2 + z3);   // z_hi partial for A's epilogue
    }
    __syncthreads();   // B1: rhp + zh ready; phase-1 php reads complete

    const int inext = i + RNN_BLOCKS;
    if (!ks) {
      // ---- A: phase 2 + epilogue, all in-register (no part[], no B2)
      const float zhi = zh[h];
      // prefetch next node's A-rows early; latency hides under the Uh dot
      float azn = 0.f, ahn = 0.f;
      if (inext < N_NODES) {
        azn = Az[(size_t)inext * HID + h];
        ahn = Ah[(size_t)inext * HID + h];
      }
      const float4* rq = (const float4*)rhp;
      float c0 = 0.f, c1 = 0.f, c2 = 0.f, c3 = 0.f;
#pragma unroll
      for (int q = 0; q < 32; ++q) {
        float4 blk = rq[q];
        c0 = dot2f(big[4 * q + 0], f2h2(blk.x), c0);
        c1 = dot2f(big[4 * q + 1], f2h2(blk.y), c1);
        c2 = dot2f(big[4 * q + 2], f2h2(blk.z), c2);
        c3 = dot2f(big[4 * q + 3], f2h2(blk.w), c3);
      }
      const float g  = fast_sigmoid(az + bzv + (z0 + z1) + (z2 + z3) + zhi);
      const float c  = fast_tanh(ah + bhv + (c0 + c1) + (c2 + c3));
      const float hn = fmaf(g, phv, (1.f - g) * c);
      float nb = __shfl_xor(hn, 1, 64);   // DPP xor-1
      if ((h & 1) == 0) {                 // handoff store FIRST (children poll this)
        __hip_atomic_store(&HpkU[(size_t)i * (HID / 2) + (h >> 1)],
                           __builtin_bit_cast(unsigned, pkrtz(hn, nb)),
                           __ATOMIC_RELAXED, __HIP_MEMORY_SCOPE_AGENT);
      }
      H[(size_t)i * HID + h] = hn;        // fp32 row for leafmax (off critical path)
      az = azn; ah = ahn;
    } else {
      // ---- B: poll next node's parent, overlapped with A's phase2+epilogue
      if (inext < N_NODES) {
        ar = Ar[(size_t)inext * HID + h];
        const int pn = edge[2 * inext];   // parent, pn < inext
        if (tl < HID / 2) {
          unsigned v = __hip_atomic_load(&HpkU[(size_t)pn * (HID / 2) + tl],
                                         __ATOMIC_RELAXED, __HIP_MEMORY_SCOPE_AGENT);
          long spin = 0;
          while (v == POISON) {
            if (++spin > (1L << 22)) break;   // escape hatch (should never trigger)
            v = __hip_atomic_load(&HpkU[(size_t)pn * (HID / 2) + tl],
                                  __ATOMIC_RELAXED, __HIP_MEMORY_SCOPE_AGENT);
          }
          php[tl] = __builtin_bit_cast(half2_t, v);
        }
      }
    }
    // loop -> B0 joins A's epilogue with B's poll before any php/rhp/zh reuse
  }
}

// ---------------------------------------------------------------- leaf max partial (64 blocks x 32 leaves)
__global__ void leafmax_kernel(const float* __restrict__ H, const int* __restrict__ leafs,
                               float* __restrict__ partial) {
  int b = blockIdx.x;
  int h = threadIdx.x;
  float m = -INFINITY;
#pragma unroll 4
  for (int j = 0; j < N_LEAF / 64; ++j) {
    int node = leafs[b * (N_LEAF / 64) + j];
    m = fmaxf(m, H[(size_t)node * HID + h]);
  }
  partial[b * HID + h] = m;
}

// ---------------------------------------------------------------- final: reduce partials, W_out, softmax, loss
__global__ void final_kernel(const float* __restrict__ partial, const float* __restrict__ W_out,
                             const float* __restrict__ b_out, const float* __restrict__ y,
                             float* __restrict__ out) {
  int h = threadIdx.x;
  float m = -INFINITY;
#pragma unroll 8
  for (int b = 0; b < 64; ++b) m = fmaxf(m, partial[b * HID + h]);
  __shared__ float fs[HID];
  __shared__ float red[HID];
  __shared__ float logit[NCLASS];
  fs[h] = m;
  __syncthreads();
  for (int c = 0; c < NCLASS; ++c) {
    red[h] = W_out[c * HID + h] * fs[h];
    __syncthreads();
    for (int s = HID / 2; s > 0; s >>= 1) {
      if (h < s) red[h] += red[h + s];
      __syncthreads();
    }
    if (h == 0) logit[c] = red[0] + b_out[c];
    __syncthreads();
  }
  if (h == 0) {
    float mx = logit[0];
    for (int c = 1; c < NCLASS; ++c) mx = fmaxf(mx, logit[c]);
    float e[NCLASS], s = 0.f;
    for (int c = 0; c < NCLASS; ++c) { e[c] = expf(logit[c] - mx); s += e[c]; }
    float loss = 0.f;
    for (int c = 0; c < NCLASS; ++c) {
      float p = e[c] / s;
      out[c] = p;
      float d = y[c] - p;
      loss += d * d;
    }
    out[NCLASS] = loss;
  }
}

// ---------------------------------------------------------------- launch
extern "C" void kernel_launch(void* const* d_in, const int* in_sizes, int n_in,
                              void* d_out, int out_size, void* d_ws, size_t ws_size,
                              hipStream_t stream) {
  const int*   tree = (const int*)d_in[0];
  const int*   edge = (const int*)d_in[1];
  const int*   leaf = (const int*)d_in[2];
  const float* y    = (const float*)d_in[3];
  const float* E    = (const float*)d_in[4];
  const float* Wz   = (const float*)d_in[5];
  const float* Uz   = (const float*)d_in[6];
  const float* bz   = (const float*)d_in[7];
  const float* Wr   = (const float*)d_in[8];
  const float* Ur   = (const float*)d_in[9];
  const float* br   = (const float*)d_in[10];
  const float* Wh   = (const float*)d_in[11];
  const float* Uh   = (const float*)d_in[12];
  const float* bh   = (const float*)d_in[13];
  const float* Wout = (const float*)d_in[14];
  const float* bout = (const float*)d_in[15];
  float* out = (float*)d_out;

  char* base = (char*)d_ws;
  size_t b = 0;
  _Float16* ETh = (_Float16*)(base + b); b += (size_t)VOCAB * HID * 2;      // 25.7 MB
  b = (b + 255) & ~(size_t)255;
  half2_t* Upk = (half2_t*)(base + b); b += (size_t)3 * 4 * 8192 * 4;       // 98304 half2
  half2_t* Hpk = (half2_t*)(base + b); b += (size_t)N_NODES * (HID / 2) * 4;
  float* X   = (float*)(base + b); b += (size_t)N_NODES * HID * 4;
  float* Az  = (float*)(base + b); b += (size_t)N_NODES * HID * 4;
  float* Ar  = (float*)(base + b); b += (size_t)N_NODES * HID * 4;
  float* Ah  = (float*)(base + b); b += (size_t)N_NODES * HID * 4;
  float* H   = (float*)(base + b); b += (size_t)N_NODES * HID * 4;
  float* partial = (float*)(base + b); b += (size_t)64 * HID * 4;

  poison_hpk_kernel<<<(N_NODES * (HID / 2) + 255) / 256, 256, 0, stream>>>((unsigned*)Hpk);
  transpose_f16_kernel<<<dim3((VOCAB + 31) / 32, HID / 32), dim3(32, 8), 0, stream>>>(E, ETh, HID, VOCAB);
  pack_u_kernel<<<12, 256, 0, stream>>>(Uz, Ur, Uh, Upk);
  gather_x_kernel<<<N_NODES, 128, 0, stream>>>(tree, (const half2_t*)ETh, X, H, Hpk);
  gemm3_kernel<<<dim3(N_NODES / 64, HID / 64, 3), 256, 0, stream>>>(X, Wz, Wr, Wh, Az, Ar, Ah);
  rnn_kernel<<<RNN_BLOCKS, 512, 0, stream>>>(Az, Ar, Ah, Upk, bz, br, bh, edge, H, (unsigned*)Hpk);
  leafmax_kernel<<<64, HID, 0, stream>>>(H, leaf, partial);
  final_kernel<<<1, HID, 0, stream>>>(partial, Wout, bout, y, out);
}

// Round 5
// 516.221 us; speedup vs baseline: 1.3674x; 1.3674x over previous
//
#include <hip/hip_runtime.h>
#include <math.h>

#define N_NODES 4096
#define WORDS   64
#define HID     256
#define VOCAB   50257
#define NCLASS  4
#define N_LEAF  2048
#define RNN_BLOCKS 256     // 1 block/CU -> all resident, spin-wait safe
#define POISON 0x7FFF7FFFu // half2 (NaN,NaN); finite packed rows never match

typedef _Float16 half2_t __attribute__((ext_vector_type(2)));

__device__ __forceinline__ float dot2f(half2_t a, half2_t b, float c) {
#if __has_builtin(__builtin_amdgcn_fdot2)
  return __builtin_amdgcn_fdot2(a, b, c, false);   // v_dot2_f32_f16
#else
  return c + (float)a.x * (float)b.x + (float)a.y * (float)b.y;
#endif
}

__device__ __forceinline__ half2_t f2h2(float f) {
  union { float f; half2_t h; } u; u.f = f; return u.h;
}

__device__ __forceinline__ float fast_rcp(float x) { return __builtin_amdgcn_rcpf(x); }
__device__ __forceinline__ float fast_sigmoid(float x) {        // rcp-based, no IEEE div seq
  return fast_rcp(1.f + __expf(-x));
}
__device__ __forceinline__ float fast_tanh(float x) {           // 1 - 2/(e^{2x}+1); saturates to +-1
  return 1.f - 2.f * fast_rcp(1.f + __expf(2.f * x));
}
__device__ __forceinline__ half2_t pkrtz(float a, float b) {    // single v_cvt_pkrtz_f16_f32
#if __has_builtin(__builtin_amdgcn_cvt_pkrtz)
  return __builtin_bit_cast(half2_t, __builtin_amdgcn_cvt_pkrtz(a, b));
#else
  half2_t v; v.x = (_Float16)a; v.y = (_Float16)b; return v;
#endif
}

// ---------------------------------------------------------------- poison Hpk (the handoff medium)
__global__ void poison_hpk_kernel(unsigned* __restrict__ HpkU) {
  int i = blockIdx.x * blockDim.x + threadIdx.x;
  if (i < N_NODES * (HID / 2)) HpkU[i] = POISON;
}

// ---------------------------------------------------------------- E (HID,VOCAB) f32 -> ETh (VOCAB,HID) f16
__global__ void transpose_f16_kernel(const float* __restrict__ src, _Float16* __restrict__ dst,
                                     int R, int C) {
  __shared__ float tile[32][33];
  int c0 = blockIdx.x * 32, r0 = blockIdx.y * 32;
  int tx = threadIdx.x, ty = threadIdx.y;
#pragma unroll
  for (int j = 0; j < 32; j += 8) {
    int c = c0 + tx, r = r0 + ty + j;
    if (c < C) tile[ty + j][tx] = src[(size_t)r * C + c];
  }
  __syncthreads();
#pragma unroll
  for (int j = 0; j < 32; j += 8) {
    int c = c0 + ty + j, r = r0 + tx;
    if (c < C) dst[(size_t)c * R + r] = (_Float16)tile[tx][ty + j];
  }
}

// ---------------------------------------------------------------- pack U and W -> half2
// Layout: packed[m][kp][h] = (M[h][2kp], M[h][2kp+1]), linear idx (m*4+s)*8192 + j*256 + h
// with kp = s*32+j. m = 0..5 -> Uz,Ur,Uh,Wz,Wr,Wh. Same algebra serves the rnn U-dots and
// the fused GEMV (A[i][n] = sum_k X[i][k] W[n][k] -> dot2(packed[m][kp][n], Xpair[kp])).
__global__ void __launch_bounds__(256) pack_u_kernel(
    const float* __restrict__ Uz, const float* __restrict__ Ur, const float* __restrict__ Uh,
    const float* __restrict__ Wz, const float* __restrict__ Wr, const float* __restrict__ Wh,
    half2_t* __restrict__ Upk) {
  __shared__ float tile[64][259];
  int m = blockIdx.x >> 2, g = blockIdx.x & 3;
  const float* U = m == 0 ? Uz : (m == 1 ? Ur : (m == 2 ? Uh : (m == 3 ? Wz : (m == 4 ? Wr : Wh))));
  int t = threadIdx.x;
  for (int r = 0; r < 64; ++r) tile[r][t] = U[(size_t)(g * 64 + r) * 256 + t];
  __syncthreads();
#pragma unroll
  for (int it = 0; it < 32; ++it) {
    int e = it * 256 + t;
    int hl = e & 63, kj = e >> 6, s = kj >> 5, j = kj & 31;
    half2_t v;
    v.x = (_Float16)tile[hl][s * 64 + 2 * j];
    v.y = (_Float16)tile[hl][s * 64 + 2 * j + 1];
    Upk[(size_t)(m * 4 + s) * 8192 + j * 256 + (g * 64 + hl)] = v;
  }
}

// ---------------------------------------------------------------- fused gather + 3-gate GEMV
// R15: replaces gather_x_kernel + gemm3_kernel. One block per 4 nodes, 256 threads.
// Phase A: gather X rows (thread t: half2 col t&127, word-half t>>7) -> f16 pairs in LDS.
// Phase B: A_m[i][n] = sum_kp dot2(Wpk[m][kp][n], Xh[i][kp]); 4-node blocking reuses each
// W load 4x (L2 traffic /4 vs 1-node GEMV). Kills the 16MB X round-trip + a dispatch.
__global__ void __launch_bounds__(256) gather_gemv_kernel(
    const int* __restrict__ tree, const half2_t* __restrict__ ETh2,
    const half2_t* __restrict__ Upk,
    float* __restrict__ Az, float* __restrict__ Ar, float* __restrict__ Ah,
    float* __restrict__ H, half2_t* __restrict__ Hpk) {
  const int t  = threadIdx.x;
  const int i0 = blockIdx.x * 4;
  __shared__ int     vsf[4 * WORDS];       // 4 nodes' word ids (contiguous in tree)
  __shared__ float2  ps[256];              // gather partial sums
  __shared__ half2_t Xh[4][HID / 2];       // 4 nodes' X rows, f16 pairs

  vsf[t] = tree[(size_t)i0 * WORDS + t];   // 4*64 = 256 words, coalesced
  __syncthreads();

  const int c    = t & 127;                // half2 column
  const int half = t >> 7;                 // word-half
#pragma unroll
  for (int n = 0; n < 4; ++n) {
    float ax = 0.f, ay = 0.f;
    const int base = n * WORDS + half * 32;
#pragma unroll 8
    for (int w = 0; w < 32; ++w) {
      half2_t e = ETh2[(size_t)vsf[base + w] * (HID / 2) + c];
      ax += (float)e.x;
      ay += (float)e.y;
    }
    ps[t].x = ax; ps[t].y = ay;
    __syncthreads();
    if (t < 128) {
      float xx = ps[t].x + ps[t + 128].x;
      float yy = ps[t].y + ps[t + 128].y;
      half2_t hv; hv.x = (_Float16)xx; hv.y = (_Float16)yy;   // RNE casts (match old gather)
      Xh[n][t] = hv;
      if (i0 + n == 0) {                   // node 0: seed fp32 H row + packed Hpk row
        float2 v2; v2.x = xx; v2.y = yy;
        ((float2*)H)[t] = v2;
        Hpk[t] = hv;
      }
    }
    __syncthreads();                       // ps reusable; Xh[n] visible to all
  }

  // ---- GEMV: 3 gates x 4 nodes, output neuron = t
  float acc[3][4];
#pragma unroll
  for (int m = 0; m < 3; ++m)
#pragma unroll
    for (int n = 0; n < 4; ++n) acc[m][n] = 0.f;

  const half2_t* wb = Upk + (size_t)12 * 8192 + t;   // m=3 (Wz) base, +32768 per gate
#pragma unroll 8
  for (int kp = 0; kp < 128; ++kp) {
    half2_t w0 = wb[kp * 256];
    half2_t w1 = wb[kp * 256 + 32768];
    half2_t w2 = wb[kp * 256 + 65536];
    half2_t x0 = Xh[0][kp], x1 = Xh[1][kp], x2 = Xh[2][kp], x3 = Xh[3][kp];  // LDS broadcast
    acc[0][0] = dot2f(w0, x0, acc[0][0]); acc[0][1] = dot2f(w0, x1, acc[0][1]);
    acc[0][2] = dot2f(w0, x2, acc[0][2]); acc[0][3] = dot2f(w0, x3, acc[0][3]);
    acc[1][0] = dot2f(w1, x0, acc[1][0]); acc[1][1] = dot2f(w1, x1, acc[1][1]);
    acc[1][2] = dot2f(w1, x2, acc[1][2]); acc[1][3] = dot2f(w1, x3, acc[1][3]);
    acc[2][0] = dot2f(w2, x0, acc[2][0]); acc[2][1] = dot2f(w2, x1, acc[2][1]);
    acc[2][2] = dot2f(w2, x2, acc[2][2]); acc[2][3] = dot2f(w2, x3, acc[2][3]);
  }
#pragma unroll
  for (int n = 0; n < 4; ++n) {
    Az[(size_t)(i0 + n) * HID + t] = acc[0][n];
    Ar[(size_t)(i0 + n) * HID + t] = acc[1][n];
    Ah[(size_t)(i0 + n) * HID + t] = acc[2][n];
  }
}

// ---------------------------------------------------------------- persistent wavefront GRU scan (block-cyclic)
// R15: EXACT restore of the R0 333us structure (two redesigns regressed: R1 contiguous
// segments serialized program order, 2ms; R14 asymmetric A/B split lengthened the serial
// dot chain pre/post-B1, 537us). R9 protocol (pollable rows, no flags/fences) + R10 fast
// epilogue. Only delta vs R0: spin escape 1<<26 -> 1<<22 (diagnosable poison instead of a
// container-killing hang if a protocol bug ever appears).
// All U loops FULLY unrolled (R6 lesson: partial unroll -> alloca -> LDS/scratch catastrophe).
__global__ void
__attribute__((amdgpu_flat_work_group_size(512, 512), amdgpu_waves_per_eu(2, 2)))
rnn_kernel(
    const float* __restrict__ Az, const float* __restrict__ Ar, const float* __restrict__ Ah,
    const half2_t* __restrict__ Upk,
    const float* __restrict__ bz, const float* __restrict__ br, const float* __restrict__ bh,
    const int* __restrict__ edge, float* __restrict__ H, unsigned* HpkU) {
  const int tid = threadIdx.x;
  const int h   = tid & (HID - 1);
  const int ks  = tid >> 8;            // 0..1
  __shared__ half2_t php[HID / 2];
  __shared__ half2_t rhp[HID / 2];
  __shared__ float   part[2 * HID];

  // one-time U load (full unroll -> SSA -> register file)
  half2_t um[128];   // Uz (ks0) or Ur (ks1), full K
  half2_t uhh[64];   // Uh, k-slice [ks*128, ks*128+128)
  {
    const half2_t* mb = Upk + (size_t)(ks ? 4 : 0) * 8192 + h;
#pragma unroll
    for (int j = 0; j < 128; ++j)
      um[j] = mb[(j >> 5) * 8192 + (j & 31) * 256];
    const half2_t* hb = Upk + (size_t)(8 + 2 * ks) * 8192 + h;
#pragma unroll
    for (int j = 0; j < 64; ++j)
      uhh[j] = hb[(j >> 5) * 8192 + (j & 31) * 256];
  }
  const float b1  = ks ? br[h] : bz[h];
  const float bhv = ks ? 0.f : bh[h];

  const int istart = blockIdx.x == 0 ? RNN_BLOCKS : blockIdx.x;  // node 0 pre-seeded by gather
  for (int i = istart; i < N_NODES; i += RNN_BLOCKS) {
    const int p = edge[2 * i];   // parent, p < i
    // A-row loads issued before the poll; they complete while waiting
    const float a1 = ks ? Ar[(size_t)i * HID + h] : Az[(size_t)i * HID + h];
    const float a2 = ks ? 0.f : Ah[(size_t)i * HID + h];

    if (tid < HID / 2) {
      unsigned v = __hip_atomic_load(&HpkU[(size_t)p * (HID / 2) + tid],
                                     __ATOMIC_RELAXED, __HIP_MEMORY_SCOPE_AGENT);
      long spin = 0;
      while (v == POISON) {
        if (++spin > (1L << 22)) break;   // escape hatch (should never trigger)
        v = __hip_atomic_load(&HpkU[(size_t)p * (HID / 2) + tid],
                              __ATOMIC_RELAXED, __HIP_MEMORY_SCOPE_AGENT);
      }
      php[tid] = __builtin_bit_cast(half2_t, v);
    }
    __syncthreads();   // B0: packed parent row resident in LDS

    // parent element for this h, decoded from fp16 row
    half2_t ph2 = php[h >> 1];
    const float phv = (float)((h & 1) ? ph2.y : ph2.x);

    // phase 1: full-K dot of Uz (ks0) / Ur (ks1) against packed parent row
    float ac0 = a1 + b1, ac1 = 0.f, ac2 = 0.f, ac3 = 0.f;
    {
      const float4* phq = (const float4*)php;
#pragma unroll
      for (int q = 0; q < 32; ++q) {
        float4 blk = phq[q];
        ac0 = dot2f(um[4 * q + 0], f2h2(blk.x), ac0);
        ac1 = dot2f(um[4 * q + 1], f2h2(blk.y), ac1);
        ac2 = dot2f(um[4 * q + 2], f2h2(blk.z), ac2);
        ac3 = dot2f(um[4 * q + 3], f2h2(blk.w), ac3);
      }
    }
    const float g = fast_sigmoid((ac0 + ac1) + (ac2 + ac3));
    if (ks) {                    // r gate -> packed r*ph
      float rh = g * phv;
      float nb = __shfl_xor(rh, 1, 64);
      if ((h & 1) == 0) rhp[h >> 1] = pkrtz(rh, nb);
    }
    __syncthreads();   // B1

    // phase 2: Uh partial dots over this thread's k-slice
    float c0 = 0.f, c1 = 0.f;
    {
      const float4* rq = (const float4*)(rhp + ks * 64);
#pragma unroll
      for (int q = 0; q < 16; ++q) {
        float4 blk = rq[q];
        c0 = dot2f(uhh[4 * q + 0], f2h2(blk.x), c0);
        c1 = dot2f(uhh[4 * q + 1], f2h2(blk.y), c1);
        c0 = dot2f(uhh[4 * q + 2], f2h2(blk.z), c0);
        c1 = dot2f(uhh[4 * q + 3], f2h2(blk.w), c1);
      }
    }
    part[ks * HID + h] = c0 + c1;
    __syncthreads();   // B2

    if (ks == 0) {
      float ca = a2 + bhv + part[h] + part[HID + h];
      float c  = fast_tanh(ca);
      float hn = fmaf(g, phv, (1.f - g) * c);
      float nb = __shfl_xor(hn, 1, 64);   // DPP xor-1
      if ((h & 1) == 0) {                 // handoff store FIRST (children poll this)
        __hip_atomic_store(&HpkU[(size_t)i * (HID / 2) + (h >> 1)],
                           __builtin_bit_cast(unsigned, pkrtz(hn, nb)),
                           __ATOMIC_RELAXED, __HIP_MEMORY_SCOPE_AGENT);
      }
      H[(size_t)i * HID + h] = hn;        // fp32 row for leafmax (off critical path)
    }
    // no publish barrier, no waitcnt, no flag: the row stores are the signal
  }
}

// ---------------------------------------------------------------- leaf max partial (64 blocks x 32 leaves)
__global__ void leafmax_kernel(const float* __restrict__ H, const int* __restrict__ leafs,
                               float* __restrict__ partial) {
  int b = blockIdx.x;
  int h = threadIdx.x;
  float m = -INFINITY;
#pragma unroll 4
  for (int j = 0; j < N_LEAF / 64; ++j) {
    int node = leafs[b * (N_LEAF / 64) + j];
    m = fmaxf(m, H[(size_t)node * HID + h]);
  }
  partial[b * HID + h] = m;
}

// ---------------------------------------------------------------- final: reduce partials, W_out, softmax, loss
__global__ void final_kernel(const float* __restrict__ partial, const float* __restrict__ W_out,
                             const float* __restrict__ b_out, const float* __restrict__ y,
                             float* __restrict__ out) {
  int h = threadIdx.x;
  float m = -INFINITY;
#pragma unroll 8
  for (int b = 0; b < 64; ++b) m = fmaxf(m, partial[b * HID + h]);
  __shared__ float fs[HID];
  __shared__ float red[HID];
  __shared__ float logit[NCLASS];
  fs[h] = m;
  __syncthreads();
  for (int c = 0; c < NCLASS; ++c) {
    red[h] = W_out[c * HID + h] * fs[h];
    __syncthreads();
    for (int s = HID / 2; s > 0; s >>= 1) {
      if (h < s) red[h] += red[h + s];
      __syncthreads();
    }
    if (h == 0) logit[c] = red[0] + b_out[c];
    __syncthreads();
  }
  if (h == 0) {
    float mx = logit[0];
    for (int c = 1; c < NCLASS; ++c) mx = fmaxf(mx, logit[c]);
    float e[NCLASS], s = 0.f;
    for (int c = 0; c < NCLASS; ++c) { e[c] = expf(logit[c] - mx); s += e[c]; }
    float loss = 0.f;
    for (int c = 0; c < NCLASS; ++c) {
      float p = e[c] / s;
      out[c] = p;
      float d = y[c] - p;
      loss += d * d;
    }
    out[NCLASS] = loss;
  }
}

// ---------------------------------------------------------------- launch
extern "C" void kernel_launch(void* const* d_in, const int* in_sizes, int n_in,
                              void* d_out, int out_size, void* d_ws, size_t ws_size,
                              hipStream_t stream) {
  const int*   tree = (const int*)d_in[0];
  const int*   edge = (const int*)d_in[1];
  const int*   leaf = (const int*)d_in[2];
  const float* y    = (const float*)d_in[3];
  const float* E    = (const float*)d_in[4];
  const float* Wz   = (const float*)d_in[5];
  const float* Uz   = (const float*)d_in[6];
  const float* bz   = (const float*)d_in[7];
  const float* Wr   = (const float*)d_in[8];
  const float* Ur   = (const float*)d_in[9];
  const float* br   = (const float*)d_in[10];
  const float* Wh   = (const float*)d_in[11];
  const float* Uh   = (const float*)d_in[12];
  const float* bh   = (const float*)d_in[13];
  const float* Wout = (const float*)d_in[14];
  const float* bout = (const float*)d_in[15];
  float* out = (float*)d_out;

  char* base = (char*)d_ws;
  size_t b = 0;
  _Float16* ETh = (_Float16*)(base + b); b += (size_t)VOCAB * HID * 2;      // 25.7 MB
  b = (b + 255) & ~(size_t)255;
  half2_t* Upk = (half2_t*)(base + b); b += (size_t)6 * 4 * 8192 * 4;       // U(3) + W(3) packed
  half2_t* Hpk = (half2_t*)(base + b); b += (size_t)N_NODES * (HID / 2) * 4;
  float* Az  = (float*)(base + b); b += (size_t)N_NODES * HID * 4;
  float* Ar  = (float*)(base + b); b += (size_t)N_NODES * HID * 4;
  float* Ah  = (float*)(base + b); b += (size_t)N_NODES * HID * 4;
  float* H   = (float*)(base + b); b += (size_t)N_NODES * HID * 4;
  float* partial = (float*)(base + b); b += (size_t)64 * HID * 4;

  poison_hpk_kernel<<<(N_NODES * (HID / 2) + 255) / 256, 256, 0, stream>>>((unsigned*)Hpk);
  transpose_f16_kernel<<<dim3((VOCAB + 31) / 32, HID / 32), dim3(32, 8), 0, stream>>>(E, ETh, HID, VOCAB);
  pack_u_kernel<<<24, 256, 0, stream>>>(Uz, Ur, Uh, Wz, Wr, Wh, Upk);
  gather_gemv_kernel<<<N_NODES / 4, 256, 0, stream>>>(tree, (const half2_t*)ETh, Upk,
                                                      Az, Ar, Ah, H, Hpk);
  rnn_kernel<<<RNN_BLOCKS, 512, 0, stream>>>(Az, Ar, Ah, Upk, bz, br, bh, edge, H, (unsigned*)Hpk);
  leafmax_kernel<<<64, HID, 0, stream>>>(H, leaf, partial);
  final_kernel<<<1, HID, 0, stream>>>(partial, Wout, bout, y, out);
}